// Round 1
// baseline (24.660 us; speedup 1.0000x reference)
//
#include <hip/hip_runtime.h>
#include <float.h>

// Problem dims (fixed by reference)
#define B_TOK 256
#define N_OUT 512
#define K_IN  1024

constexpr int BG = 8;            // b rows per stage-1 block (register micro-tile)
constexpr int KS = 8;            // k splits
constexpr int KC = K_IN / KS;    // 128 k per chunk

// ---------------- Stage 1: partial max/min over one K chunk ----------------
// grid: (B_TOK/BG) x KS ; block: 512 threads (thread = one output column n)
__global__ __launch_bounds__(512)
void mam_stage1(const float* __restrict__ x, const float* __restrict__ w,
                float* __restrict__ pmx, float* __restrict__ pmn) {
    const int n  = threadIdx.x;                 // 0..511
    const int g  = blockIdx.x;                  // b-group
    const int c  = blockIdx.y;                  // k-chunk
    const int b0 = g * BG;
    const int kc = c * KC;

    const float* wrow  = w + (size_t)n * K_IN + kc;   // weight[n][kc..]
    const float* xbase = x + (size_t)b0 * K_IN + kc;  // wave-uniform addresses

    float mx[BG], mn[BG];
#pragma unroll
    for (int r = 0; r < BG; ++r) { mx[r] = -FLT_MAX; mn[r] = FLT_MAX; }

#pragma unroll 4
    for (int kk = 0; kk < KC; kk += 4) {
        const float4 wv = *reinterpret_cast<const float4*>(wrow + kk);
#pragma unroll
        for (int r = 0; r < BG; ++r) {
            const float4 xv = *reinterpret_cast<const float4*>(xbase + (size_t)r * K_IN + kk);
            const float p0 = xv.x * wv.x;
            const float p1 = xv.y * wv.y;
            const float p2 = xv.z * wv.z;
            const float p3 = xv.w * wv.w;
            mx[r] = fmaxf(fmaxf(mx[r], p0), p1);   // -> v_max3 candidates
            mx[r] = fmaxf(fmaxf(mx[r], p2), p3);
            mn[r] = fminf(fminf(mn[r], p0), p1);
            mn[r] = fminf(fminf(mn[r], p2), p3);
        }
    }

    const size_t plane = (size_t)B_TOK * N_OUT;
    const size_t base  = (size_t)c * plane + (size_t)b0 * N_OUT + n;
#pragma unroll
    for (int r = 0; r < BG; ++r) {
        pmx[base + (size_t)r * N_OUT] = mx[r];
        pmn[base + (size_t)r * N_OUT] = mn[r];
    }
}

// ---------------- Stage 2: combine partials + bias ----------------
__global__ __launch_bounds__(256)
void mam_stage2(const float* __restrict__ pmx, const float* __restrict__ pmn,
                const float* __restrict__ bias, float* __restrict__ out) {
    const int idx = blockIdx.x * 256 + threadIdx.x;   // 0..131071
    const size_t plane = (size_t)B_TOK * N_OUT;
    float mx = -FLT_MAX, mn = FLT_MAX;
#pragma unroll
    for (int cc = 0; cc < KS; ++cc) {
        mx = fmaxf(mx, pmx[(size_t)cc * plane + idx]);
        mn = fminf(mn, pmn[(size_t)cc * plane + idx]);
    }
    out[idx] = mx + mn + bias[idx & (N_OUT - 1)];
}

// ---------------- Fallback (if workspace too small): one thread per output ----------------
__global__ __launch_bounds__(256)
void mam_simple(const float* __restrict__ x, const float* __restrict__ w,
                const float* __restrict__ bias, float* __restrict__ out) {
    const int idx = blockIdx.x * 256 + threadIdx.x;
    const int b = idx / N_OUT, n = idx % N_OUT;
    const float* xr = x + (size_t)b * K_IN;
    const float* wr = w + (size_t)n * K_IN;
    float mx = -FLT_MAX, mn = FLT_MAX;
#pragma unroll 4
    for (int k = 0; k < K_IN; k += 4) {
        const float4 xv = *reinterpret_cast<const float4*>(xr + k);
        const float4 wv = *reinterpret_cast<const float4*>(wr + k);
        const float p0 = xv.x * wv.x, p1 = xv.y * wv.y;
        const float p2 = xv.z * wv.z, p3 = xv.w * wv.w;
        mx = fmaxf(fmaxf(mx, p0), p1);
        mx = fmaxf(fmaxf(mx, p2), p3);
        mn = fminf(fminf(mn, p0), p1);
        mn = fminf(fminf(mn, p2), p3);
    }
    out[idx] = mx + mn + bias[n];
}

extern "C" void kernel_launch(void* const* d_in, const int* in_sizes, int n_in,
                              void* d_out, int out_size, void* d_ws, size_t ws_size,
                              hipStream_t stream) {
    const float* x    = (const float*)d_in[0];   // [256,1024]
    const float* w    = (const float*)d_in[1];   // [512,1024]  (torch layout [n][k])
    const float* bias = (const float*)d_in[2];   // [512]
    float* out = (float*)d_out;                  // [256,512] f32

    const size_t plane = (size_t)B_TOK * N_OUT;
    const size_t need  = 2 * (size_t)KS * plane * sizeof(float);  // 8 MB

    if (ws_size >= need) {
        float* pmx = (float*)d_ws;
        float* pmn = pmx + (size_t)KS * plane;
        dim3 g1(B_TOK / BG, KS);
        mam_stage1<<<g1, 512, 0, stream>>>(x, w, pmx, pmn);
        mam_stage2<<<(int)(plane / 256), 256, 0, stream>>>(pmx, pmn, bias, out);
    } else {
        mam_simple<<<(int)(plane / 256), 256, 0, stream>>>(x, w, bias, out);
    }
}